// Round 10
// baseline (386.992 us; speedup 1.0000x reference)
//
#include <hip/hip_runtime.h>
#include <hip/hip_bf16.h>

typedef __attribute__((ext_vector_type(8)))  short short8;
typedef __attribute__((ext_vector_type(16))) float f32x16;

#define DIM   64
#define K_CL  512
#define N_PTS 524288
#define OUTSZ (K_CL * DIM + K_CL)   // 33280

// pack two fp32 -> one u32 of 2x bf16 (RNE) via compiler cvt_pk path
__device__ inline unsigned int pk_bf16(float a, float b) {
    float2 t; t.x = a; t.y = b;
    __hip_bfloat162 h2 = __float22bfloat162_rn(t);
    unsigned int u;
    __builtin_memcpy(&u, &h2, 4);
    return u;
}

// split float4 -> 2 u32 of bf16-hi, 2 u32 of bf16-lo
__device__ inline void split4(const float4& v, unsigned int hw[2], unsigned int lw[2]) {
    hw[0] = pk_bf16(v.x, v.y);
    hw[1] = pk_bf16(v.z, v.w);
    float hx = __builtin_bit_cast(float, hw[0] << 16);
    float hy = __builtin_bit_cast(float, hw[0] & 0xFFFF0000u);
    float hz = __builtin_bit_cast(float, hw[1] << 16);
    float hv = __builtin_bit_cast(float, hw[1] & 0xFFFF0000u);
    lw[0] = pk_bf16(v.x - hx, v.y - hy);
    lw[1] = pk_bf16(v.z - hz, v.w - hv);
}

// ---------------------------------------------------------------------------
// prep: one 64-lane block per center. hc2 = 0.5*||c||^2 (shuffle reduce);
// chi/clo = bf16 hi/lo of NEGATED center.
// ---------------------------------------------------------------------------
__global__ __launch_bounds__(64)
void prep_kernel(const float* __restrict__ c,
                 unsigned short* __restrict__ chi,
                 unsigned short* __restrict__ clo,
                 float* __restrict__ hc2) {
    const int k = blockIdx.x, d = threadIdx.x;
    float v = c[k * DIM + d];
    float s = v * v;
#pragma unroll
    for (int off = 1; off < 64; off <<= 1) s += __shfl_xor(s, off, 64);

    float nv = -v;
    unsigned int u  = __builtin_bit_cast(unsigned int, nv);
    unsigned int hr = (u + 0x7FFFu + ((u >> 16) & 1u)) & 0xFFFF0000u;
    chi[k * DIM + d] = (unsigned short)(hr >> 16);
    float lo = nv - __builtin_bit_cast(float, hr);
    unsigned int ul = __builtin_bit_cast(unsigned int, lo);
    unsigned int lr = ul + 0x7FFFu + ((ul >> 16) & 1u);
    clo[k * DIM + d] = (unsigned short)(lr >> 16);
    if (d == 0) hc2[k] = 0.5f * s;
}

// ---------------------------------------------------------------------------
// assign (unchanged from round 8): double-buffered staging, one barrier per
// tile, depth-2 prefetch, centers resident in VGPRs, u64 atomicMin winner.
// ---------------------------------------------------------------------------
__global__ __launch_bounds__(512, 4)
void assign_kernel(const float* __restrict__ x,
                   const unsigned short* __restrict__ chi_g,
                   const unsigned short* __restrict__ clo_g,
                   const float* __restrict__ hc2g,
                   unsigned int* __restrict__ assign) {
    __shared__ unsigned int lds_xh[2][1024];
    __shared__ unsigned int lds_xl[2][1024];
    __shared__ float lds_bias[512];
    __shared__ unsigned long long lds_best[256];

    const int tid  = threadIdx.x;
    const int wave = tid >> 6;
    const int lane = tid & 63;
    const int l31  = lane & 31;
    const int h    = lane >> 5;

    if (tid < 256) lds_best[tid] = ~0ull;
    {
        int w = tid >> 6, ct = (tid >> 5) & 1, hh = (tid >> 4) & 1, r = tid & 15;
        lds_bias[tid] = hc2g[w * 64 + ct * 32 + (r & 3) + 8 * (r >> 2) + 4 * hh];
    }

    short8 cH[2][4], cL[2][4];
#pragma unroll
    for (int ct = 0; ct < 2; ++ct) {
        int row = wave * 64 + ct * 32 + l31;
#pragma unroll
        for (int ks = 0; ks < 4; ++ks) {
            size_t off = (size_t)row * DIM + ks * 16 + h * 8;
            cH[ct][ks] = *(const short8*)(chi_g + off);
            cL[ct][ks] = *(const short8*)(clo_g + off);
        }
    }

    const int p_st  = tid >> 4;
    const int dgrp  = tid & 15;
    const int f_st  = dgrp >> 1;
    const int half  = dgrp & 1;
    const int widx  = f_st * 128 + ((p_st ^ (f_st & 7)) << 2) + half * 2;

    const size_t xbase = (size_t)blockIdx.x * 16384 + tid * 4;

#define STAGE(buf, v4)                                                        \
    {                                                                         \
        unsigned int hw2[2], lw2[2];                                          \
        split4(v4, hw2, lw2);                                                 \
        uint2 w2;                                                             \
        w2.x = hw2[0]; w2.y = hw2[1]; *(uint2*)&lds_xh[buf][widx] = w2;       \
        w2.x = lw2[0]; w2.y = lw2[1]; *(uint2*)&lds_xl[buf][widx] = w2;       \
    }

    float4 pf = *(const float4*)(x + xbase);
    STAGE(0, pf)
    pf = *(const float4*)(x + xbase + 2048);
    __syncthreads();

    const unsigned int base_id = wave * 64 + 4 * h;

    for (int t = 0; t < 8; ++t) {
        const int b = t & 1;
        if (t < 7) STAGE(b ^ 1, pf)
        if (t < 6) pf = *(const float4*)(x + xbase + (size_t)(t + 2) * 2048);

        f32x16 acc0, acc1;
        {
            const float4* b0 = (const float4*)&lds_bias[wave * 64 + h * 16];
            const float4* b1 = (const float4*)&lds_bias[wave * 64 + 32 + h * 16];
#pragma unroll
            for (int g = 0; g < 4; ++g) {
                float4 a = b0[g], bb = b1[g];
                acc0[4*g+0] = a.x;  acc0[4*g+1] = a.y;  acc0[4*g+2] = a.z;  acc0[4*g+3] = a.w;
                acc1[4*g+0] = bb.x; acc1[4*g+1] = bb.y; acc1[4*g+2] = bb.z; acc1[4*g+3] = bb.w;
            }
        }

#pragma unroll
        for (int ks = 0; ks < 4; ++ks) {
            const int f = ks * 2 + h;
            const int ridx = f * 128 + ((l31 ^ (f & 7)) << 2);
            short8 xh = *(const short8*)&lds_xh[b][ridx];
            short8 xl = *(const short8*)&lds_xl[b][ridx];
            acc0 = __builtin_amdgcn_mfma_f32_32x32x16_bf16(cH[0][ks], xh, acc0, 0, 0, 0);
            acc1 = __builtin_amdgcn_mfma_f32_32x32x16_bf16(cH[1][ks], xh, acc1, 0, 0, 0);
            acc0 = __builtin_amdgcn_mfma_f32_32x32x16_bf16(cH[0][ks], xl, acc0, 0, 0, 0);
            acc1 = __builtin_amdgcn_mfma_f32_32x32x16_bf16(cH[1][ks], xl, acc1, 0, 0, 0);
            acc0 = __builtin_amdgcn_mfma_f32_32x32x16_bf16(cL[0][ks], xh, acc0, 0, 0, 0);
            acc1 = __builtin_amdgcn_mfma_f32_32x32x16_bf16(cL[1][ks], xh, acc1, 0, 0, 0);
        }

        float bv = acc0[0];
        unsigned int boff = 0;
#pragma unroll
        for (int r = 1; r < 16; ++r) {
            unsigned int off = (r & 3) + 8 * (r >> 2);
            if (acc0[r] < bv) { bv = acc0[r]; boff = off; }
        }
#pragma unroll
        for (int r = 0; r < 16; ++r) {
            unsigned int off = 32 + (r & 3) + 8 * (r >> 2);
            if (acc1[r] < bv) { bv = acc1[r]; boff = off; }
        }

        unsigned int ub = __builtin_bit_cast(unsigned int, bv);
        ub ^= (unsigned int)(((int)ub) >> 31) | 0x80000000u;
        unsigned long long pk =
            ((unsigned long long)ub << 32) | (unsigned long long)(base_id + boff);
        atomicMin(&lds_best[t * 32 + l31], pk);
        __syncthreads();
    }
#undef STAGE

    if (tid < 256)
        assign[blockIdx.x * 256 + tid] = (unsigned int)(lds_best[tid] & 0xFFFFFFFFu);
}

// ---------------------------------------------------------------------------
// reduce v5: one-hot MFMA, bf16-hi B operand; flush EITHER to a private
// bf16-packed slab (SLAB=1, non-atomic coalesced streaming) or via global
// atomics (SLAB=0 fallback). nsc = superchunks of 128 points per block.
// Slab layout per block: u32[512*32], entry [k][p] = pack(sum(k,p), sum(k,p+32)).
// ---------------------------------------------------------------------------
template <int SLAB>
__global__ __launch_bounds__(512)
void reduce_kernel(const float* __restrict__ x,
                   const unsigned int* __restrict__ assign,
                   float* __restrict__ gsums, float* __restrict__ gcnt,
                   unsigned int* __restrict__ slab_u32,
                   float* __restrict__ cnt_slab, int nsc) {
    __shared__ unsigned short lds_h[2][64][128];
    __shared__ unsigned int   lds_a[2][128];
    __shared__ float          lds_cnt[K_CL];

    const int tid  = threadIdx.x;
    const int wave = tid >> 6;
    const int lane = tid & 63;
    const int l31  = lane & 31;
    const int h    = lane >> 5;
    const int d    = lane;
    const int pg   = wave;

    lds_cnt[tid] = 0.f;

    const size_t pbase = (size_t)blockIdx.x * (size_t)(nsc * 128);

    float f[16];
    {
        const float* xp = x + (pbase + pg * 16) * DIM + d;
#pragma unroll
        for (int i = 0; i < 16; ++i) f[i] = xp[(size_t)i * DIM];
    }
    __syncthreads();

    for (int i = 0; i < (nsc >> 2); ++i)
        atomicAdd(&lds_cnt[assign[pbase + tid + i * 512]], 1.f);

    const int swz = (d & 15) << 3;

#define WRITE_BUF(b)                                                          \
    {                                                                         \
        unsigned int hw[8];                                                   \
        _Pragma("unroll")                                                     \
        for (int q = 0; q < 8; ++q) hw[q] = pk_bf16(f[2*q], f[2*q+1]);        \
        unsigned short* rh = &lds_h[b][d][0];                                 \
        const int j0 = (pg * 16) ^ swz;                                       \
        const int j1 = (pg * 16 + 8) ^ swz;                                   \
        uint4 u;                                                              \
        u.x=hw[0]; u.y=hw[1]; u.z=hw[2]; u.w=hw[3]; *(uint4*)&rh[j0] = u;     \
        u.x=hw[4]; u.y=hw[5]; u.z=hw[6]; u.w=hw[7]; *(uint4*)&rh[j1] = u;     \
    }

    WRITE_BUF(0)
    if (tid < 32) {
        uint4 av = *(const uint4*)(assign + pbase + tid * 4);
        *(uint4*)&lds_a[0][tid * 4] = av;
    }
    __syncthreads();

    const unsigned int row0 = wave * 64 + l31;
    const unsigned int row1 = row0 + 32;
    f32x16 C00 = {}, C01 = {}, C10 = {}, C11 = {};

    for (int sc = 0; sc < nsc; ++sc) {
        const int b = sc & 1;
        if (sc < nsc - 1) {
            const float* xp = x + (pbase + (size_t)(sc + 1) * 128 + pg * 16) * DIM + d;
#pragma unroll
            for (int i = 0; i < 16; ++i) f[i] = xp[(size_t)i * DIM];
        }

#pragma unroll
        for (int c = 0; c < 8; ++c) {
            const unsigned int* ap = &lds_a[b][c * 16 + 8 * h];
            uint4 aA = *(const uint4*)ap;
            uint4 aB = *(const uint4*)(ap + 4);
            unsigned int a[8] = {aA.x, aA.y, aA.z, aA.w, aB.x, aB.y, aB.z, aB.w};
            unsigned int i0[4], i1[4];
#pragma unroll
            for (int q = 0; q < 4; ++q) {
                i0[q] = (a[2*q]==row0 ? 0x3F80u : 0u) | (a[2*q+1]==row0 ? 0x3F800000u : 0u);
                i1[q] = (a[2*q]==row1 ? 0x3F80u : 0u) | (a[2*q+1]==row1 ? 0x3F800000u : 0u);
            }
            uint4 u0; u0.x=i0[0]; u0.y=i0[1]; u0.z=i0[2]; u0.w=i0[3];
            uint4 u1; u1.x=i1[0]; u1.y=i1[1]; u1.z=i1[2]; u1.w=i1[3];
            short8 A0 = __builtin_bit_cast(short8, u0);
            short8 A1 = __builtin_bit_cast(short8, u1);

            const int off = (c * 16 + 8 * h) ^ ((l31 & 15) << 3);
            short8 xh0 = *(const short8*)&lds_h[b][l31][off];
            short8 xh1 = *(const short8*)&lds_h[b][l31 + 32][off];

            C00 = __builtin_amdgcn_mfma_f32_32x32x16_bf16(A0, xh0, C00, 0, 0, 0);
            C01 = __builtin_amdgcn_mfma_f32_32x32x16_bf16(A0, xh1, C01, 0, 0, 0);
            C10 = __builtin_amdgcn_mfma_f32_32x32x16_bf16(A1, xh0, C10, 0, 0, 0);
            C11 = __builtin_amdgcn_mfma_f32_32x32x16_bf16(A1, xh1, C11, 0, 0, 0);
        }
        __syncthreads();

        if (sc < nsc - 1) {
            WRITE_BUF(b ^ 1)
            if (tid < 32) {
                uint4 av = *(const uint4*)(assign + pbase + (size_t)(sc + 1) * 128 + tid * 4);
                *(uint4*)&lds_a[b ^ 1][tid * 4] = av;
            }
            __syncthreads();
        }
    }
#undef WRITE_BUF

    if (SLAB) {
        cnt_slab[blockIdx.x * K_CL + tid] = lds_cnt[tid];
        unsigned int* myslab = slab_u32 + (size_t)blockIdx.x * 16384;
#pragma unroll
        for (int r = 0; r < 16; ++r) {
            int ro = (r & 3) + 8 * (r >> 2) + 4 * h;
            int k0 = wave * 64 + ro;
            myslab[k0 * 32 + l31]        = pk_bf16(C00[r], C01[r]);
            myslab[(k0 + 32) * 32 + l31] = pk_bf16(C10[r], C11[r]);
        }
    } else {
        atomicAdd(&gcnt[tid], lds_cnt[tid]);
#pragma unroll
        for (int rr = 0; rr < 16; ++rr) {
            int r = (rr + (int)(blockIdx.x & 15)) & 15;
            int ro = (r & 3) + 8 * (r >> 2) + 4 * h;
            atomicAdd(&gsums[(wave * 64 + ro) * DIM + l31],           C00[r]);
            atomicAdd(&gsums[(wave * 64 + ro) * DIM + 32 + l31],      C01[r]);
            atomicAdd(&gsums[(wave * 64 + 32 + ro) * DIM + l31],      C10[r]);
            atomicAdd(&gsums[(wave * 64 + 32 + ro) * DIM + 32 + l31], C11[r]);
        }
    }
}

// ---------------------------------------------------------------------------
// csum: sum per-block count slabs -> gcnt
// ---------------------------------------------------------------------------
__global__ __launch_bounds__(64)
void csum_kernel(const float* __restrict__ cnt_slab,
                 float* __restrict__ gcnt, int P) {
    int k = blockIdx.x * 64 + threadIdx.x;
    float s = 0.f;
    for (int b = 0; b < P; ++b) s += cnt_slab[b * K_CL + k];
    gcnt[k] = s;
}

// ---------------------------------------------------------------------------
// final (slab path): sum bf16-packed slabs, divide, fallback, counts
// thread gid -> (k = gid>>5, p = gid&31) produces outputs (k,p) and (k,p+32)
// ---------------------------------------------------------------------------
__global__ __launch_bounds__(256)
void final_slab_kernel(const unsigned int* __restrict__ slab,
                       const float* __restrict__ gcnt,
                       const float* __restrict__ centers,
                       float* __restrict__ out, int P) {
    int gid = blockIdx.x * 256 + threadIdx.x;   // 0..16383
    int k = gid >> 5, p = gid & 31;
    float s0 = 0.f, s1 = 0.f;
    for (int b = 0; b < P; ++b) {
        unsigned int u = slab[(size_t)b * 16384 + k * 32 + p];
        s0 += __builtin_bit_cast(float, u << 16);
        s1 += __builtin_bit_cast(float, u & 0xFFFF0000u);
    }
    float c = gcnt[k];
    if (c > 0.f) {
        out[k * DIM + p]      = s0 / c;
        out[k * DIM + 32 + p] = s1 / c;
    } else {
        out[k * DIM + p]      = centers[k * DIM + p];
        out[k * DIM + 32 + p] = centers[k * DIM + 32 + p];
    }
    if (p == 0) out[K_CL * DIM + k] = c;
}

// ---------------------------------------------------------------------------
// final (atomic path): means + fallback + counts from gsums/gcnt
// ---------------------------------------------------------------------------
__global__ void final_kernel(const float* __restrict__ gsums,
                             const float* __restrict__ gcnt,
                             const float* __restrict__ centers,
                             float* __restrict__ out) {
    int i = blockIdx.x * 256 + threadIdx.x;
    if (i < K_CL * DIM) {
        int k = i >> 6;
        float c = gcnt[k];
        out[i] = (c > 0.f) ? (gsums[i] / c) : centers[i];
    } else if (i < OUTSZ) {
        out[i] = gcnt[i - K_CL * DIM];
    }
}

extern "C" void kernel_launch(void* const* d_in, const int* in_sizes, int n_in,
                              void* d_out, int out_size, void* d_ws, size_t ws_size,
                              hipStream_t stream) {
    const float* x       = (const float*)d_in[0];
    const float* centers = (const float*)d_in[1];

    char* ws = (char*)d_ws;
    unsigned short* chi    = (unsigned short*)(ws);             // 64 KiB
    unsigned short* clo    = (unsigned short*)(ws + 65536);     // 64 KiB
    float*          hc2    = (float*)(ws + 131072);             // 2 KiB
    unsigned int*   assign = (unsigned int*)(ws + 133120);      // 2 MiB
    float*          gsums  = (float*)(ws + 2230272);            // 128 KiB
    float*          gcnt   = (float*)(ws + 2361344);            // 2 KiB
    const size_t    fixed  = 2363392;
    unsigned int*   slab_u32 = (unsigned int*)(ws + fixed);              // 32 MiB
    float*          cnt_slab = (float*)(ws + fixed + (size_t)512*16384*4); // 1 MiB
    const size_t    need = fixed + (size_t)512*16384*4 + (size_t)512*K_CL*4;

    prep_kernel<<<K_CL, 64, 0, stream>>>(centers, chi, clo, hc2);
    assign_kernel<<<2048, 512, 0, stream>>>(x, chi, clo, hc2, assign);

    if (ws_size >= need) {
        // slab path: 512 blocks x 1024 pts, non-atomic bf16 slab flush
        reduce_kernel<1><<<512, 512, 0, stream>>>(x, assign, gsums, gcnt,
                                                  slab_u32, cnt_slab, 8);
        csum_kernel<<<8, 64, 0, stream>>>(cnt_slab, gcnt, 512);
        final_slab_kernel<<<64, 256, 0, stream>>>(slab_u32, gcnt, centers,
                                                  (float*)d_out, 512);
    } else {
        // atomic fallback: 256 blocks x 2048 pts (half the atomic storm)
        hipMemsetAsync(gsums, 0, (K_CL * DIM + K_CL) * sizeof(float), stream);
        reduce_kernel<0><<<256, 512, 0, stream>>>(x, assign, gsums, gcnt,
                                                  slab_u32, cnt_slab, 16);
        final_kernel<<<(OUTSZ + 255) / 256, 256, 0, stream>>>(
            gsums, gcnt, centers, (float*)d_out);
    }
}

// Round 11
// 160.457 us; speedup vs baseline: 2.4118x; 2.4118x over previous
//
#include <hip/hip_runtime.h>
#include <hip/hip_bf16.h>

typedef __attribute__((ext_vector_type(8)))  short short8;
typedef __attribute__((ext_vector_type(16))) float f32x16;

#define DIM   64
#define K_CL  512
#define N_PTS 524288
#define OUTSZ (K_CL * DIM + K_CL)   // 33280

// pack two fp32 -> one u32 of 2x bf16 (RNE) via compiler cvt_pk path
__device__ inline unsigned int pk_bf16(float a, float b) {
    float2 t; t.x = a; t.y = b;
    __hip_bfloat162 h2 = __float22bfloat162_rn(t);
    unsigned int u;
    __builtin_memcpy(&u, &h2, 4);
    return u;
}

// split float4 -> 2 u32 of bf16-hi, 2 u32 of bf16-lo
__device__ inline void split4(const float4& v, unsigned int hw[2], unsigned int lw[2]) {
    hw[0] = pk_bf16(v.x, v.y);
    hw[1] = pk_bf16(v.z, v.w);
    float hx = __builtin_bit_cast(float, hw[0] << 16);
    float hy = __builtin_bit_cast(float, hw[0] & 0xFFFF0000u);
    float hz = __builtin_bit_cast(float, hw[1] << 16);
    float hv = __builtin_bit_cast(float, hw[1] & 0xFFFF0000u);
    lw[0] = pk_bf16(v.x - hx, v.y - hy);
    lw[1] = pk_bf16(v.z - hz, v.w - hv);
}

// ---------------------------------------------------------------------------
// prep: one 64-lane block per center. hc2 = 0.5*||c||^2 (shuffle reduce);
// chi/clo = bf16 hi/lo of NEGATED center.
// ---------------------------------------------------------------------------
__global__ __launch_bounds__(64)
void prep_kernel(const float* __restrict__ c,
                 unsigned short* __restrict__ chi,
                 unsigned short* __restrict__ clo,
                 float* __restrict__ hc2) {
    const int k = blockIdx.x, d = threadIdx.x;
    float v = c[k * DIM + d];
    float s = v * v;
#pragma unroll
    for (int off = 1; off < 64; off <<= 1) s += __shfl_xor(s, off, 64);

    float nv = -v;
    unsigned int u  = __builtin_bit_cast(unsigned int, nv);
    unsigned int hr = (u + 0x7FFFu + ((u >> 16) & 1u)) & 0xFFFF0000u;
    chi[k * DIM + d] = (unsigned short)(hr >> 16);
    float lo = nv - __builtin_bit_cast(float, hr);
    unsigned int ul = __builtin_bit_cast(unsigned int, lo);
    unsigned int lr = ul + 0x7FFFu + ((ul >> 16) & 1u);
    clo[k * DIM + d] = (unsigned short)(lr >> 16);
    if (d == 0) hc2[k] = 0.5f * s;
}

// ---------------------------------------------------------------------------
// assign (unchanged): double-buffered staging, one barrier per tile,
// depth-2 prefetch, centers resident in VGPRs, u64 atomicMin winner.
// ---------------------------------------------------------------------------
__global__ __launch_bounds__(512, 4)
void assign_kernel(const float* __restrict__ x,
                   const unsigned short* __restrict__ chi_g,
                   const unsigned short* __restrict__ clo_g,
                   const float* __restrict__ hc2g,
                   unsigned int* __restrict__ assign) {
    __shared__ unsigned int lds_xh[2][1024];
    __shared__ unsigned int lds_xl[2][1024];
    __shared__ float lds_bias[512];
    __shared__ unsigned long long lds_best[256];

    const int tid  = threadIdx.x;
    const int wave = tid >> 6;
    const int lane = tid & 63;
    const int l31  = lane & 31;
    const int h    = lane >> 5;

    if (tid < 256) lds_best[tid] = ~0ull;
    {
        int w = tid >> 6, ct = (tid >> 5) & 1, hh = (tid >> 4) & 1, r = tid & 15;
        lds_bias[tid] = hc2g[w * 64 + ct * 32 + (r & 3) + 8 * (r >> 2) + 4 * hh];
    }

    short8 cH[2][4], cL[2][4];
#pragma unroll
    for (int ct = 0; ct < 2; ++ct) {
        int row = wave * 64 + ct * 32 + l31;
#pragma unroll
        for (int ks = 0; ks < 4; ++ks) {
            size_t off = (size_t)row * DIM + ks * 16 + h * 8;
            cH[ct][ks] = *(const short8*)(chi_g + off);
            cL[ct][ks] = *(const short8*)(clo_g + off);
        }
    }

    const int p_st  = tid >> 4;
    const int dgrp  = tid & 15;
    const int f_st  = dgrp >> 1;
    const int half  = dgrp & 1;
    const int widx  = f_st * 128 + ((p_st ^ (f_st & 7)) << 2) + half * 2;

    const size_t xbase = (size_t)blockIdx.x * 16384 + tid * 4;

#define STAGE(buf, v4)                                                        \
    {                                                                         \
        unsigned int hw2[2], lw2[2];                                          \
        split4(v4, hw2, lw2);                                                 \
        uint2 w2;                                                             \
        w2.x = hw2[0]; w2.y = hw2[1]; *(uint2*)&lds_xh[buf][widx] = w2;       \
        w2.x = lw2[0]; w2.y = lw2[1]; *(uint2*)&lds_xl[buf][widx] = w2;       \
    }

    float4 pf = *(const float4*)(x + xbase);
    STAGE(0, pf)
    pf = *(const float4*)(x + xbase + 2048);
    __syncthreads();

    const unsigned int base_id = wave * 64 + 4 * h;

    for (int t = 0; t < 8; ++t) {
        const int b = t & 1;
        if (t < 7) STAGE(b ^ 1, pf)
        if (t < 6) pf = *(const float4*)(x + xbase + (size_t)(t + 2) * 2048);

        f32x16 acc0, acc1;
        {
            const float4* b0 = (const float4*)&lds_bias[wave * 64 + h * 16];
            const float4* b1 = (const float4*)&lds_bias[wave * 64 + 32 + h * 16];
#pragma unroll
            for (int g = 0; g < 4; ++g) {
                float4 a = b0[g], bb = b1[g];
                acc0[4*g+0] = a.x;  acc0[4*g+1] = a.y;  acc0[4*g+2] = a.z;  acc0[4*g+3] = a.w;
                acc1[4*g+0] = bb.x; acc1[4*g+1] = bb.y; acc1[4*g+2] = bb.z; acc1[4*g+3] = bb.w;
            }
        }

#pragma unroll
        for (int ks = 0; ks < 4; ++ks) {
            const int f = ks * 2 + h;
            const int ridx = f * 128 + ((l31 ^ (f & 7)) << 2);
            short8 xh = *(const short8*)&lds_xh[b][ridx];
            short8 xl = *(const short8*)&lds_xl[b][ridx];
            acc0 = __builtin_amdgcn_mfma_f32_32x32x16_bf16(cH[0][ks], xh, acc0, 0, 0, 0);
            acc1 = __builtin_amdgcn_mfma_f32_32x32x16_bf16(cH[1][ks], xh, acc1, 0, 0, 0);
            acc0 = __builtin_amdgcn_mfma_f32_32x32x16_bf16(cH[0][ks], xl, acc0, 0, 0, 0);
            acc1 = __builtin_amdgcn_mfma_f32_32x32x16_bf16(cH[1][ks], xl, acc1, 0, 0, 0);
            acc0 = __builtin_amdgcn_mfma_f32_32x32x16_bf16(cL[0][ks], xh, acc0, 0, 0, 0);
            acc1 = __builtin_amdgcn_mfma_f32_32x32x16_bf16(cL[1][ks], xh, acc1, 0, 0, 0);
        }

        float bv = acc0[0];
        unsigned int boff = 0;
#pragma unroll
        for (int r = 1; r < 16; ++r) {
            unsigned int off = (r & 3) + 8 * (r >> 2);
            if (acc0[r] < bv) { bv = acc0[r]; boff = off; }
        }
#pragma unroll
        for (int r = 0; r < 16; ++r) {
            unsigned int off = 32 + (r & 3) + 8 * (r >> 2);
            if (acc1[r] < bv) { bv = acc1[r]; boff = off; }
        }

        unsigned int ub = __builtin_bit_cast(unsigned int, bv);
        ub ^= (unsigned int)(((int)ub) >> 31) | 0x80000000u;
        unsigned long long pk =
            ((unsigned long long)ub << 32) | (unsigned long long)(base_id + boff);
        atomicMin(&lds_best[t * 32 + l31], pk);
        __syncthreads();
    }
#undef STAGE

    if (tid < 256)
        assign[blockIdx.x * 256 + tid] = (unsigned int)(lds_best[tid] & 0xFFFFFFFFu);
}

// ---------------------------------------------------------------------------
// reduce v5 (unchanged): one-hot MFMA, bf16-hi B operand; slab or atomic flush.
// ---------------------------------------------------------------------------
template <int SLAB>
__global__ __launch_bounds__(512)
void reduce_kernel(const float* __restrict__ x,
                   const unsigned int* __restrict__ assign,
                   float* __restrict__ gsums, float* __restrict__ gcnt,
                   unsigned int* __restrict__ slab_u32,
                   float* __restrict__ cnt_slab, int nsc) {
    __shared__ unsigned short lds_h[2][64][128];
    __shared__ unsigned int   lds_a[2][128];
    __shared__ float          lds_cnt[K_CL];

    const int tid  = threadIdx.x;
    const int wave = tid >> 6;
    const int lane = tid & 63;
    const int l31  = lane & 31;
    const int h    = lane >> 5;
    const int d    = lane;
    const int pg   = wave;

    lds_cnt[tid] = 0.f;

    const size_t pbase = (size_t)blockIdx.x * (size_t)(nsc * 128);

    float f[16];
    {
        const float* xp = x + (pbase + pg * 16) * DIM + d;
#pragma unroll
        for (int i = 0; i < 16; ++i) f[i] = xp[(size_t)i * DIM];
    }
    __syncthreads();

    for (int i = 0; i < (nsc >> 2); ++i)
        atomicAdd(&lds_cnt[assign[pbase + tid + i * 512]], 1.f);

    const int swz = (d & 15) << 3;

#define WRITE_BUF(b)                                                          \
    {                                                                         \
        unsigned int hw[8];                                                   \
        _Pragma("unroll")                                                     \
        for (int q = 0; q < 8; ++q) hw[q] = pk_bf16(f[2*q], f[2*q+1]);        \
        unsigned short* rh = &lds_h[b][d][0];                                 \
        const int j0 = (pg * 16) ^ swz;                                       \
        const int j1 = (pg * 16 + 8) ^ swz;                                   \
        uint4 u;                                                              \
        u.x=hw[0]; u.y=hw[1]; u.z=hw[2]; u.w=hw[3]; *(uint4*)&rh[j0] = u;     \
        u.x=hw[4]; u.y=hw[5]; u.z=hw[6]; u.w=hw[7]; *(uint4*)&rh[j1] = u;     \
    }

    WRITE_BUF(0)
    if (tid < 32) {
        uint4 av = *(const uint4*)(assign + pbase + tid * 4);
        *(uint4*)&lds_a[0][tid * 4] = av;
    }
    __syncthreads();

    const unsigned int row0 = wave * 64 + l31;
    const unsigned int row1 = row0 + 32;
    f32x16 C00 = {}, C01 = {}, C10 = {}, C11 = {};

    for (int sc = 0; sc < nsc; ++sc) {
        const int b = sc & 1;
        if (sc < nsc - 1) {
            const float* xp = x + (pbase + (size_t)(sc + 1) * 128 + pg * 16) * DIM + d;
#pragma unroll
            for (int i = 0; i < 16; ++i) f[i] = xp[(size_t)i * DIM];
        }

#pragma unroll
        for (int c = 0; c < 8; ++c) {
            const unsigned int* ap = &lds_a[b][c * 16 + 8 * h];
            uint4 aA = *(const uint4*)ap;
            uint4 aB = *(const uint4*)(ap + 4);
            unsigned int a[8] = {aA.x, aA.y, aA.z, aA.w, aB.x, aB.y, aB.z, aB.w};
            unsigned int i0[4], i1[4];
#pragma unroll
            for (int q = 0; q < 4; ++q) {
                i0[q] = (a[2*q]==row0 ? 0x3F80u : 0u) | (a[2*q+1]==row0 ? 0x3F800000u : 0u);
                i1[q] = (a[2*q]==row1 ? 0x3F80u : 0u) | (a[2*q+1]==row1 ? 0x3F800000u : 0u);
            }
            uint4 u0; u0.x=i0[0]; u0.y=i0[1]; u0.z=i0[2]; u0.w=i0[3];
            uint4 u1; u1.x=i1[0]; u1.y=i1[1]; u1.z=i1[2]; u1.w=i1[3];
            short8 A0 = __builtin_bit_cast(short8, u0);
            short8 A1 = __builtin_bit_cast(short8, u1);

            const int off = (c * 16 + 8 * h) ^ ((l31 & 15) << 3);
            short8 xh0 = *(const short8*)&lds_h[b][l31][off];
            short8 xh1 = *(const short8*)&lds_h[b][l31 + 32][off];

            C00 = __builtin_amdgcn_mfma_f32_32x32x16_bf16(A0, xh0, C00, 0, 0, 0);
            C01 = __builtin_amdgcn_mfma_f32_32x32x16_bf16(A0, xh1, C01, 0, 0, 0);
            C10 = __builtin_amdgcn_mfma_f32_32x32x16_bf16(A1, xh0, C10, 0, 0, 0);
            C11 = __builtin_amdgcn_mfma_f32_32x32x16_bf16(A1, xh1, C11, 0, 0, 0);
        }
        __syncthreads();

        if (sc < nsc - 1) {
            WRITE_BUF(b ^ 1)
            if (tid < 32) {
                uint4 av = *(const uint4*)(assign + pbase + (size_t)(sc + 1) * 128 + tid * 4);
                *(uint4*)&lds_a[b ^ 1][tid * 4] = av;
            }
            __syncthreads();
        }
    }
#undef WRITE_BUF

    if (SLAB) {
        cnt_slab[blockIdx.x * K_CL + tid] = lds_cnt[tid];
        unsigned int* myslab = slab_u32 + (size_t)blockIdx.x * 16384;
#pragma unroll
        for (int r = 0; r < 16; ++r) {
            int ro = (r & 3) + 8 * (r >> 2) + 4 * h;
            int k0 = wave * 64 + ro;
            myslab[k0 * 32 + l31]        = pk_bf16(C00[r], C01[r]);
            myslab[(k0 + 32) * 32 + l31] = pk_bf16(C10[r], C11[r]);
        }
    } else {
        atomicAdd(&gcnt[tid], lds_cnt[tid]);
#pragma unroll
        for (int rr = 0; rr < 16; ++rr) {
            int r = (rr + (int)(blockIdx.x & 15)) & 15;
            int ro = (r & 3) + 8 * (r >> 2) + 4 * h;
            atomicAdd(&gsums[(wave * 64 + ro) * DIM + l31],           C00[r]);
            atomicAdd(&gsums[(wave * 64 + ro) * DIM + 32 + l31],      C01[r]);
            atomicAdd(&gsums[(wave * 64 + 32 + ro) * DIM + l31],      C10[r]);
            atomicAdd(&gsums[(wave * 64 + 32 + ro) * DIM + 32 + l31], C11[r]);
        }
    }
}

// ---------------------------------------------------------------------------
// csum v2: gcnt[k] = sum_b cnt_slab[b][k]. 64 blocks x 256 thr; thread
// (s=tid>>3 in [0,32), kl=tid&7): k = blk*8+kl, sums 16 slabs (b=s+32j);
// LDS reduce 32 partials per k.
// ---------------------------------------------------------------------------
__global__ __launch_bounds__(256)
void csum_kernel(const float* __restrict__ cnt_slab,
                 float* __restrict__ gcnt, int P) {
    __shared__ float red[32][8];
    const int s  = threadIdx.x >> 3;
    const int kl = threadIdx.x & 7;
    const int k  = blockIdx.x * 8 + kl;
    float acc = 0.f;
    for (int b = s; b < P; b += 32) acc += cnt_slab[b * K_CL + k];
    red[s][kl] = acc;
    __syncthreads();
    if (threadIdx.x < 8) {
        float t = 0.f;
#pragma unroll
        for (int j = 0; j < 32; ++j) t += red[j][threadIdx.x];
        gcnt[blockIdx.x * 8 + threadIdx.x] = t;
    }
}

// ---------------------------------------------------------------------------
// final (slab) v2: 256 blocks x 512 thr. Block owns 64 gids; thread
// (q=tid>>6 in [0,8), gl=tid&63) sums 64 slabs (b=q+8j) for gid=blk*64+gl
// -- fully coalesced 256B wave-loads, 64 independent loads/thread. LDS
// reduce over q, then 64 threads write centers + counts.
// ---------------------------------------------------------------------------
__global__ __launch_bounds__(512)
void final_slab_kernel(const unsigned int* __restrict__ slab,
                       const float* __restrict__ gcnt,
                       const float* __restrict__ centers,
                       float* __restrict__ out, int P) {
    __shared__ float s0b[8][64], s1b[8][64];
    const int q  = threadIdx.x >> 6;
    const int gl = threadIdx.x & 63;
    const int gid = blockIdx.x * 64 + gl;      // 0..16383

    float s0 = 0.f, s1 = 0.f;
    for (int b = q; b < P; b += 8) {
        unsigned int u = slab[(size_t)b * 16384 + gid];
        s0 += __builtin_bit_cast(float, u << 16);
        s1 += __builtin_bit_cast(float, u & 0xFFFF0000u);
    }
    s0b[q][gl] = s0; s1b[q][gl] = s1;
    __syncthreads();

    if (threadIdx.x < 64) {
        float t0 = 0.f, t1 = 0.f;
#pragma unroll
        for (int j = 0; j < 8; ++j) { t0 += s0b[j][threadIdx.x]; t1 += s1b[j][threadIdx.x]; }
        const int g = blockIdx.x * 64 + threadIdx.x;
        const int k = g >> 5, p = g & 31;
        float c = gcnt[k];
        if (c > 0.f) {
            out[k * DIM + p]      = t0 / c;
            out[k * DIM + 32 + p] = t1 / c;
        } else {
            out[k * DIM + p]      = centers[k * DIM + p];
            out[k * DIM + 32 + p] = centers[k * DIM + 32 + p];
        }
        if (p == 0) out[K_CL * DIM + k] = c;
    }
}

// ---------------------------------------------------------------------------
// final (atomic fallback path)
// ---------------------------------------------------------------------------
__global__ void final_kernel(const float* __restrict__ gsums,
                             const float* __restrict__ gcnt,
                             const float* __restrict__ centers,
                             float* __restrict__ out) {
    int i = blockIdx.x * 256 + threadIdx.x;
    if (i < K_CL * DIM) {
        int k = i >> 6;
        float c = gcnt[k];
        out[i] = (c > 0.f) ? (gsums[i] / c) : centers[i];
    } else if (i < OUTSZ) {
        out[i] = gcnt[i - K_CL * DIM];
    }
}

extern "C" void kernel_launch(void* const* d_in, const int* in_sizes, int n_in,
                              void* d_out, int out_size, void* d_ws, size_t ws_size,
                              hipStream_t stream) {
    const float* x       = (const float*)d_in[0];
    const float* centers = (const float*)d_in[1];

    char* ws = (char*)d_ws;
    unsigned short* chi    = (unsigned short*)(ws);             // 64 KiB
    unsigned short* clo    = (unsigned short*)(ws + 65536);     // 64 KiB
    float*          hc2    = (float*)(ws + 131072);             // 2 KiB
    unsigned int*   assign = (unsigned int*)(ws + 133120);      // 2 MiB
    float*          gsums  = (float*)(ws + 2230272);            // 128 KiB
    float*          gcnt   = (float*)(ws + 2361344);            // 2 KiB
    const size_t    fixed  = 2363392;
    unsigned int*   slab_u32 = (unsigned int*)(ws + fixed);              // 32 MiB
    float*          cnt_slab = (float*)(ws + fixed + (size_t)512*16384*4); // 1 MiB
    const size_t    need = fixed + (size_t)512*16384*4 + (size_t)512*K_CL*4;

    prep_kernel<<<K_CL, 64, 0, stream>>>(centers, chi, clo, hc2);
    assign_kernel<<<2048, 512, 0, stream>>>(x, chi, clo, hc2, assign);

    if (ws_size >= need) {
        reduce_kernel<1><<<512, 512, 0, stream>>>(x, assign, gsums, gcnt,
                                                  slab_u32, cnt_slab, 8);
        csum_kernel<<<64, 256, 0, stream>>>(cnt_slab, gcnt, 512);
        final_slab_kernel<<<256, 512, 0, stream>>>(slab_u32, gcnt, centers,
                                                   (float*)d_out, 512);
    } else {
        hipMemsetAsync(gsums, 0, (K_CL * DIM + K_CL) * sizeof(float), stream);
        reduce_kernel<0><<<256, 512, 0, stream>>>(x, assign, gsums, gcnt,
                                                  slab_u32, cnt_slab, 16);
        final_kernel<<<(OUTSZ + 255) / 256, 256, 0, stream>>>(
            gsums, gcnt, centers, (float*)d_out);
    }
}

// Round 13
// 151.701 us; speedup vs baseline: 2.5510x; 1.0577x over previous
//
#include <hip/hip_runtime.h>
#include <hip/hip_bf16.h>

typedef __attribute__((ext_vector_type(8)))  short short8;
typedef __attribute__((ext_vector_type(16))) float f32x16;

#define DIM   64
#define K_CL  512
#define N_PTS 524288
#define OUTSZ (K_CL * DIM + K_CL)   // 33280

// pack two fp32 -> one u32 of 2x bf16 (RNE) via compiler cvt_pk path
__device__ inline unsigned int pk_bf16(float a, float b) {
    float2 t; t.x = a; t.y = b;
    __hip_bfloat162 h2 = __float22bfloat162_rn(t);
    unsigned int u;
    __builtin_memcpy(&u, &h2, 4);
    return u;
}

// split float4 -> 2 u32 of bf16-hi, 2 u32 of bf16-lo
__device__ inline void split4(const float4& v, unsigned int hw[2], unsigned int lw[2]) {
    hw[0] = pk_bf16(v.x, v.y);
    hw[1] = pk_bf16(v.z, v.w);
    float hx = __builtin_bit_cast(float, hw[0] << 16);
    float hy = __builtin_bit_cast(float, hw[0] & 0xFFFF0000u);
    float hz = __builtin_bit_cast(float, hw[1] << 16);
    float hv = __builtin_bit_cast(float, hw[1] & 0xFFFF0000u);
    lw[0] = pk_bf16(v.x - hx, v.y - hy);
    lw[1] = pk_bf16(v.z - hz, v.w - hv);
}

// ---------------------------------------------------------------------------
// prep: one 64-lane block per center. hc2 = 0.5*||c||^2 (shuffle reduce);
// chi/clo = bf16 hi/lo of NEGATED center.  (reverted: no +64 bias)
// ---------------------------------------------------------------------------
__global__ __launch_bounds__(64)
void prep_kernel(const float* __restrict__ c,
                 unsigned short* __restrict__ chi,
                 unsigned short* __restrict__ clo,
                 float* __restrict__ hc2) {
    const int k = blockIdx.x, d = threadIdx.x;
    float v = c[k * DIM + d];
    float s = v * v;
#pragma unroll
    for (int off = 1; off < 64; off <<= 1) s += __shfl_xor(s, off, 64);

    float nv = -v;
    unsigned int u  = __builtin_bit_cast(unsigned int, nv);
    unsigned int hr = (u + 0x7FFFu + ((u >> 16) & 1u)) & 0xFFFF0000u;
    chi[k * DIM + d] = (unsigned short)(hr >> 16);
    float lo = nv - __builtin_bit_cast(float, hr);
    unsigned int ul = __builtin_bit_cast(unsigned int, lo);
    unsigned int lr = ul + 0x7FFFu + ((ul >> 16) & 1u);
    clo[k * DIM + d] = (unsigned short)(lr >> 16);
    if (d == 0) hc2[k] = 0.5f * s;
}

// ---------------------------------------------------------------------------
// assign (round-11 exact argmin, now 1024 blocks x 16 tiles): double-buffered
// staging, one barrier per tile, depth-2 prefetch, centers resident in VGPRs,
// EXACT float-compare argmin (proven), u64 atomicMin winner.
// Fewer blocks halve the per-block prologue (center loads + bias staging).
// ---------------------------------------------------------------------------
__global__ __launch_bounds__(512, 4)
void assign_kernel(const float* __restrict__ x,
                   const unsigned short* __restrict__ chi_g,
                   const unsigned short* __restrict__ clo_g,
                   const float* __restrict__ hc2g,
                   unsigned int* __restrict__ assign) {
    __shared__ unsigned int lds_xh[2][1024];
    __shared__ unsigned int lds_xl[2][1024];
    __shared__ float lds_bias[512];
    __shared__ unsigned long long lds_best[512];

    const int tid  = threadIdx.x;
    const int wave = tid >> 6;
    const int lane = tid & 63;
    const int l31  = lane & 31;
    const int h    = lane >> 5;

    lds_best[tid] = ~0ull;
    {
        int w = tid >> 6, ct = (tid >> 5) & 1, hh = (tid >> 4) & 1, r = tid & 15;
        lds_bias[tid] = hc2g[w * 64 + ct * 32 + (r & 3) + 8 * (r >> 2) + 4 * hh];
    }

    short8 cH[2][4], cL[2][4];
#pragma unroll
    for (int ct = 0; ct < 2; ++ct) {
        int row = wave * 64 + ct * 32 + l31;
#pragma unroll
        for (int ks = 0; ks < 4; ++ks) {
            size_t off = (size_t)row * DIM + ks * 16 + h * 8;
            cH[ct][ks] = *(const short8*)(chi_g + off);
            cL[ct][ks] = *(const short8*)(clo_g + off);
        }
    }

    const int p_st  = tid >> 4;
    const int dgrp  = tid & 15;
    const int f_st  = dgrp >> 1;
    const int half  = dgrp & 1;
    const int widx  = f_st * 128 + ((p_st ^ (f_st & 7)) << 2) + half * 2;

    const size_t xbase = (size_t)blockIdx.x * 32768 + tid * 4;

#define STAGE(buf, v4)                                                        \
    {                                                                         \
        unsigned int hw2[2], lw2[2];                                          \
        split4(v4, hw2, lw2);                                                 \
        uint2 w2;                                                             \
        w2.x = hw2[0]; w2.y = hw2[1]; *(uint2*)&lds_xh[buf][widx] = w2;       \
        w2.x = lw2[0]; w2.y = lw2[1]; *(uint2*)&lds_xl[buf][widx] = w2;       \
    }

    float4 pf = *(const float4*)(x + xbase);
    STAGE(0, pf)
    pf = *(const float4*)(x + xbase + 2048);
    __syncthreads();

    const unsigned int base_id = wave * 64 + 4 * h;

    for (int t = 0; t < 16; ++t) {
        const int b = t & 1;
        if (t < 15) STAGE(b ^ 1, pf)
        if (t < 14) pf = *(const float4*)(x + xbase + (size_t)(t + 2) * 2048);

        f32x16 acc0, acc1;
        {
            const float4* b0 = (const float4*)&lds_bias[wave * 64 + h * 16];
            const float4* b1 = (const float4*)&lds_bias[wave * 64 + 32 + h * 16];
#pragma unroll
            for (int g = 0; g < 4; ++g) {
                float4 a = b0[g], bb = b1[g];
                acc0[4*g+0] = a.x;  acc0[4*g+1] = a.y;  acc0[4*g+2] = a.z;  acc0[4*g+3] = a.w;
                acc1[4*g+0] = bb.x; acc1[4*g+1] = bb.y; acc1[4*g+2] = bb.z; acc1[4*g+3] = bb.w;
            }
        }

#pragma unroll
        for (int ks = 0; ks < 4; ++ks) {
            const int f = ks * 2 + h;
            const int ridx = f * 128 + ((l31 ^ (f & 7)) << 2);
            short8 xh = *(const short8*)&lds_xh[b][ridx];
            short8 xl = *(const short8*)&lds_xl[b][ridx];
            acc0 = __builtin_amdgcn_mfma_f32_32x32x16_bf16(cH[0][ks], xh, acc0, 0, 0, 0);
            acc1 = __builtin_amdgcn_mfma_f32_32x32x16_bf16(cH[1][ks], xh, acc1, 0, 0, 0);
            acc0 = __builtin_amdgcn_mfma_f32_32x32x16_bf16(cH[0][ks], xl, acc0, 0, 0, 0);
            acc1 = __builtin_amdgcn_mfma_f32_32x32x16_bf16(cH[1][ks], xl, acc1, 0, 0, 0);
            acc0 = __builtin_amdgcn_mfma_f32_32x32x16_bf16(cL[0][ks], xh, acc0, 0, 0, 0);
            acc1 = __builtin_amdgcn_mfma_f32_32x32x16_bf16(cL[1][ks], xh, acc1, 0, 0, 0);
        }

        // exact in-lane argmin (ids ascending -> strict < = first occurrence)
        float bv = acc0[0];
        unsigned int boff = 0;
#pragma unroll
        for (int r = 1; r < 16; ++r) {
            unsigned int off = (r & 3) + 8 * (r >> 2);
            if (acc0[r] < bv) { bv = acc0[r]; boff = off; }
        }
#pragma unroll
        for (int r = 0; r < 16; ++r) {
            unsigned int off = 32 + (r & 3) + 8 * (r >> 2);
            if (acc1[r] < bv) { bv = acc1[r]; boff = off; }
        }

        unsigned int ub = __builtin_bit_cast(unsigned int, bv);
        ub ^= (unsigned int)(((int)ub) >> 31) | 0x80000000u;
        unsigned long long pk =
            ((unsigned long long)ub << 32) | (unsigned long long)(base_id + boff);
        atomicMin(&lds_best[t * 32 + l31], pk);
        __syncthreads();
    }
#undef STAGE

    assign[blockIdx.x * 512 + tid] = (unsigned int)(lds_best[tid] & 0xFFFFFFFFu);
}

// ---------------------------------------------------------------------------
// reduce v5 (unchanged): one-hot MFMA, bf16-hi B operand; slab or atomic flush.
// ---------------------------------------------------------------------------
template <int SLAB>
__global__ __launch_bounds__(512)
void reduce_kernel(const float* __restrict__ x,
                   const unsigned int* __restrict__ assign,
                   float* __restrict__ gsums, float* __restrict__ gcnt,
                   unsigned int* __restrict__ slab_u32,
                   float* __restrict__ cnt_slab, int nsc) {
    __shared__ unsigned short lds_h[2][64][128];
    __shared__ unsigned int   lds_a[2][128];
    __shared__ float          lds_cnt[K_CL];

    const int tid  = threadIdx.x;
    const int wave = tid >> 6;
    const int lane = tid & 63;
    const int l31  = lane & 31;
    const int h    = lane >> 5;
    const int d    = lane;
    const int pg   = wave;

    lds_cnt[tid] = 0.f;

    const size_t pbase = (size_t)blockIdx.x * (size_t)(nsc * 128);

    float f[16];
    {
        const float* xp = x + (pbase + pg * 16) * DIM + d;
#pragma unroll
        for (int i = 0; i < 16; ++i) f[i] = xp[(size_t)i * DIM];
    }
    __syncthreads();

    for (int i = 0; i < (nsc >> 2); ++i)
        atomicAdd(&lds_cnt[assign[pbase + tid + i * 512]], 1.f);

    const int swz = (d & 15) << 3;

#define WRITE_BUF(b)                                                          \
    {                                                                         \
        unsigned int hw[8];                                                   \
        _Pragma("unroll")                                                     \
        for (int q = 0; q < 8; ++q) hw[q] = pk_bf16(f[2*q], f[2*q+1]);        \
        unsigned short* rh = &lds_h[b][d][0];                                 \
        const int j0 = (pg * 16) ^ swz;                                       \
        const int j1 = (pg * 16 + 8) ^ swz;                                   \
        uint4 u;                                                              \
        u.x=hw[0]; u.y=hw[1]; u.z=hw[2]; u.w=hw[3]; *(uint4*)&rh[j0] = u;     \
        u.x=hw[4]; u.y=hw[5]; u.z=hw[6]; u.w=hw[7]; *(uint4*)&rh[j1] = u;     \
    }

    WRITE_BUF(0)
    if (tid < 32) {
        uint4 av = *(const uint4*)(assign + pbase + tid * 4);
        *(uint4*)&lds_a[0][tid * 4] = av;
    }
    __syncthreads();

    const unsigned int row0 = wave * 64 + l31;
    const unsigned int row1 = row0 + 32;
    f32x16 C00 = {}, C01 = {}, C10 = {}, C11 = {};

    for (int sc = 0; sc < nsc; ++sc) {
        const int b = sc & 1;
        if (sc < nsc - 1) {
            const float* xp = x + (pbase + (size_t)(sc + 1) * 128 + pg * 16) * DIM + d;
#pragma unroll
            for (int i = 0; i < 16; ++i) f[i] = xp[(size_t)i * DIM];
        }

#pragma unroll
        for (int c = 0; c < 8; ++c) {
            const unsigned int* ap = &lds_a[b][c * 16 + 8 * h];
            uint4 aA = *(const uint4*)ap;
            uint4 aB = *(const uint4*)(ap + 4);
            unsigned int a[8] = {aA.x, aA.y, aA.z, aA.w, aB.x, aB.y, aB.z, aB.w};
            unsigned int i0[4], i1[4];
#pragma unroll
            for (int q = 0; q < 4; ++q) {
                i0[q] = (a[2*q]==row0 ? 0x3F80u : 0u) | (a[2*q+1]==row0 ? 0x3F800000u : 0u);
                i1[q] = (a[2*q]==row1 ? 0x3F80u : 0u) | (a[2*q+1]==row1 ? 0x3F800000u : 0u);
            }
            uint4 u0; u0.x=i0[0]; u0.y=i0[1]; u0.z=i0[2]; u0.w=i0[3];
            uint4 u1; u1.x=i1[0]; u1.y=i1[1]; u1.z=i1[2]; u1.w=i1[3];
            short8 A0 = __builtin_bit_cast(short8, u0);
            short8 A1 = __builtin_bit_cast(short8, u1);

            const int off = (c * 16 + 8 * h) ^ ((l31 & 15) << 3);
            short8 xh0 = *(const short8*)&lds_h[b][l31][off];
            short8 xh1 = *(const short8*)&lds_h[b][l31 + 32][off];

            C00 = __builtin_amdgcn_mfma_f32_32x32x16_bf16(A0, xh0, C00, 0, 0, 0);
            C01 = __builtin_amdgcn_mfma_f32_32x32x16_bf16(A0, xh1, C01, 0, 0, 0);
            C10 = __builtin_amdgcn_mfma_f32_32x32x16_bf16(A1, xh0, C10, 0, 0, 0);
            C11 = __builtin_amdgcn_mfma_f32_32x32x16_bf16(A1, xh1, C11, 0, 0, 0);
        }
        __syncthreads();

        if (sc < nsc - 1) {
            WRITE_BUF(b ^ 1)
            if (tid < 32) {
                uint4 av = *(const uint4*)(assign + pbase + (size_t)(sc + 1) * 128 + tid * 4);
                *(uint4*)&lds_a[b ^ 1][tid * 4] = av;
            }
            __syncthreads();
        }
    }
#undef WRITE_BUF

    if (SLAB) {
        cnt_slab[blockIdx.x * K_CL + tid] = lds_cnt[tid];
        unsigned int* myslab = slab_u32 + (size_t)blockIdx.x * 16384;
#pragma unroll
        for (int r = 0; r < 16; ++r) {
            int ro = (r & 3) + 8 * (r >> 2) + 4 * h;
            int k0 = wave * 64 + ro;
            myslab[k0 * 32 + l31]        = pk_bf16(C00[r], C01[r]);
            myslab[(k0 + 32) * 32 + l31] = pk_bf16(C10[r], C11[r]);
        }
    } else {
        atomicAdd(&gcnt[tid], lds_cnt[tid]);
#pragma unroll
        for (int rr = 0; rr < 16; ++rr) {
            int r = (rr + (int)(blockIdx.x & 15)) & 15;
            int ro = (r & 3) + 8 * (r >> 2) + 4 * h;
            atomicAdd(&gsums[(wave * 64 + ro) * DIM + l31],           C00[r]);
            atomicAdd(&gsums[(wave * 64 + ro) * DIM + 32 + l31],      C01[r]);
            atomicAdd(&gsums[(wave * 64 + 32 + ro) * DIM + l31],      C10[r]);
            atomicAdd(&gsums[(wave * 64 + 32 + ro) * DIM + 32 + l31], C11[r]);
        }
    }
}

// ---------------------------------------------------------------------------
// final (slab) v3: csum MERGED. 256 blocks x 512 thr. Block owns 64 gids
// (= clusters 2b, 2b+1). Phase 1: slab sums over 512 slabs (8-way split +
// LDS reduce). Phase 2: counts for the 2 clusters from cnt_slab (L2-hot,
// 512 thr x 2 loads + shuffle reduce). Then divide + fallback + count write.
// ---------------------------------------------------------------------------
__global__ __launch_bounds__(512)
void final_slab_kernel(const unsigned int* __restrict__ slab,
                       const float* __restrict__ cnt_slab,
                       const float* __restrict__ centers,
                       float* __restrict__ out, int P) {
    __shared__ float s0b[8][64], s1b[8][64];
    __shared__ float cfin[2];
    const int tid = threadIdx.x;
    const int q   = tid >> 6;
    const int gl  = tid & 63;
    const int gid = blockIdx.x * 64 + gl;

    float s0 = 0.f, s1 = 0.f;
    for (int b = q; b < P; b += 8) {
        unsigned int u = slab[(size_t)b * 16384 + gid];
        s0 += __builtin_bit_cast(float, u << 16);
        s1 += __builtin_bit_cast(float, u & 0xFFFF0000u);
    }
    s0b[q][gl] = s0; s1b[q][gl] = s1;

    // counts: clusters k = 2*blk + half; wave 0 -> half 0, wave 1 -> half 1
    if (tid < 128) {
        const int hf = tid >> 6;          // wave index (tid<128 => waves 0,1)
        const int ln = tid & 63;
        const int k  = blockIdx.x * 2 + hf;
        float cp = 0.f;
#pragma unroll
        for (int j = 0; j < 8; ++j)
            cp += cnt_slab[(ln + 64 * j) * K_CL + k];
#pragma unroll
        for (int off = 1; off < 64; off <<= 1) cp += __shfl_xor(cp, off, 64);
        if (ln == 0) cfin[hf] = cp;
    }
    __syncthreads();

    if (tid < 64) {
        float t0 = 0.f, t1 = 0.f;
#pragma unroll
        for (int j = 0; j < 8; ++j) { t0 += s0b[j][tid]; t1 += s1b[j][tid]; }
        const int g = blockIdx.x * 64 + tid;
        const int k = g >> 5, p = g & 31;
        float c = cfin[(tid >> 5)];
        if (c > 0.f) {
            out[k * DIM + p]      = t0 / c;
            out[k * DIM + 32 + p] = t1 / c;
        } else {
            out[k * DIM + p]      = centers[k * DIM + p];
            out[k * DIM + 32 + p] = centers[k * DIM + 32 + p];
        }
        if (p == 0) out[K_CL * DIM + k] = c;
    }
}

// ---------------------------------------------------------------------------
// final (atomic fallback path)
// ---------------------------------------------------------------------------
__global__ void final_kernel(const float* __restrict__ gsums,
                             const float* __restrict__ gcnt,
                             const float* __restrict__ centers,
                             float* __restrict__ out) {
    int i = blockIdx.x * 256 + threadIdx.x;
    if (i < K_CL * DIM) {
        int k = i >> 6;
        float c = gcnt[k];
        out[i] = (c > 0.f) ? (gsums[i] / c) : centers[i];
    } else if (i < OUTSZ) {
        out[i] = gcnt[i - K_CL * DIM];
    }
}

extern "C" void kernel_launch(void* const* d_in, const int* in_sizes, int n_in,
                              void* d_out, int out_size, void* d_ws, size_t ws_size,
                              hipStream_t stream) {
    const float* x       = (const float*)d_in[0];
    const float* centers = (const float*)d_in[1];

    char* ws = (char*)d_ws;
    unsigned short* chi    = (unsigned short*)(ws);             // 64 KiB
    unsigned short* clo    = (unsigned short*)(ws + 65536);     // 64 KiB
    float*          hc2    = (float*)(ws + 131072);             // 2 KiB
    unsigned int*   assign = (unsigned int*)(ws + 133120);      // 2 MiB
    float*          gsums  = (float*)(ws + 2230272);            // 128 KiB
    float*          gcnt   = (float*)(ws + 2361344);            // 2 KiB
    const size_t    fixed  = 2363392;
    unsigned int*   slab_u32 = (unsigned int*)(ws + fixed);              // 32 MiB
    float*          cnt_slab = (float*)(ws + fixed + (size_t)512*16384*4); // 1 MiB
    const size_t    need = fixed + (size_t)512*16384*4 + (size_t)512*K_CL*4;

    prep_kernel<<<K_CL, 64, 0, stream>>>(centers, chi, clo, hc2);
    assign_kernel<<<1024, 512, 0, stream>>>(x, chi, clo, hc2, assign);

    if (ws_size >= need) {
        reduce_kernel<1><<<512, 512, 0, stream>>>(x, assign, gsums, gcnt,
                                                  slab_u32, cnt_slab, 8);
        final_slab_kernel<<<256, 512, 0, stream>>>(slab_u32, cnt_slab, centers,
                                                   (float*)d_out, 512);
    } else {
        hipMemsetAsync(gsums, 0, (K_CL * DIM + K_CL) * sizeof(float), stream);
        reduce_kernel<0><<<256, 512, 0, stream>>>(x, assign, gsums, gcnt,
                                                  slab_u32, cnt_slab, 16);
        final_kernel<<<(OUTSZ + 255) / 256, 256, 0, stream>>>(
            gsums, gcnt, centers, (float*)d_out);
    }
}

// Round 14
// 111.107 us; speedup vs baseline: 3.4831x; 1.3654x over previous
//
#include <hip/hip_runtime.h>
#include <hip/hip_bf16.h>

typedef __attribute__((ext_vector_type(8)))  short short8;
typedef __attribute__((ext_vector_type(16))) float f32x16;
typedef _Float16 __attribute__((ext_vector_type(8))) half8;

#define DIM   64
#define K_CL  512
#define N_PTS 524288
#define OUTSZ (K_CL * DIM + K_CL)   // 33280

// pack two fp32 -> one u32 of 2x bf16 (RNE) via compiler cvt_pk path
__device__ inline unsigned int pk_bf16(float a, float b) {
    float2 t; t.x = a; t.y = b;
    __hip_bfloat162 h2 = __float22bfloat162_rn(t);
    unsigned int u;
    __builtin_memcpy(&u, &h2, 4);
    return u;
}

// convert float4 -> 4 fp16 (RNE via v_cvt_f16_f32), packed as uint2
__device__ inline uint2 cvt4_f16(const float4& v) {
    unsigned short a = __builtin_bit_cast(unsigned short, (_Float16)v.x);
    unsigned short b = __builtin_bit_cast(unsigned short, (_Float16)v.y);
    unsigned short c = __builtin_bit_cast(unsigned short, (_Float16)v.z);
    unsigned short d = __builtin_bit_cast(unsigned short, (_Float16)v.w);
    uint2 w;
    w.x = (unsigned int)a | ((unsigned int)b << 16);
    w.y = (unsigned int)c | ((unsigned int)d << 16);
    return w;
}

// ---------------------------------------------------------------------------
// prep: one 64-lane block per center. hc2 = 0.5*||c||^2 (shuffle reduce);
// chi = fp16 of NEGATED center (single plane; fp16 1-product assign).
// ---------------------------------------------------------------------------
__global__ __launch_bounds__(64)
void prep_kernel(const float* __restrict__ c,
                 unsigned short* __restrict__ chi,
                 float* __restrict__ hc2) {
    const int k = blockIdx.x, d = threadIdx.x;
    float v = c[k * DIM + d];
    float s = v * v;
#pragma unroll
    for (int off = 1; off < 64; off <<= 1) s += __shfl_xor(s, off, 64);

    chi[k * DIM + d] = __builtin_bit_cast(unsigned short, (_Float16)(-v));
    if (d == 0) hc2[k] = 0.5f * s;
}

// ---------------------------------------------------------------------------
// assign v4 (fp16 single-product): 1024 blocks x 512 thr (8 waves), 16 tiles
// of 32 points. Score error ~1.7e-3 (fp16 operand rounding) vs winner gaps
// ~1-3 => ~30 argmin flips globally (empirically anchored), far inside the
// 2% thresholds. 8 MFMA/tile (was 24). Bias (0.5||c||^2) lives in VGPRs and
// is the C-in of the ks=0 MFMA -> zero per-tile init cost. Double-buffered
// fp16 x staging, one barrier per tile, exact float argmin, u64 atomicMin.
// ---------------------------------------------------------------------------
__global__ __launch_bounds__(512, 4)
void assign_kernel(const float* __restrict__ x,
                   const unsigned short* __restrict__ chi_g,
                   const float* __restrict__ hc2g,
                   unsigned int* __restrict__ assign) {
    __shared__ unsigned int lds_x[2][1024];
    __shared__ float lds_bias[512];
    __shared__ unsigned long long lds_best[512];

    const int tid  = threadIdx.x;
    const int wave = tid >> 6;
    const int lane = tid & 63;
    const int l31  = lane & 31;
    const int h    = lane >> 5;

    lds_best[tid] = ~0ull;
    {   // bias table in acc-register order
        int w = tid >> 6, ct = (tid >> 5) & 1, hh = (tid >> 4) & 1, r = tid & 15;
        lds_bias[tid] = hc2g[w * 64 + ct * 32 + (r & 3) + 8 * (r >> 2) + 4 * hh];
    }

    // resident center fragments: single fp16 plane (32 VGPRs)
    half8 cH[2][4];
#pragma unroll
    for (int ct = 0; ct < 2; ++ct) {
        int row = wave * 64 + ct * 32 + l31;
#pragma unroll
        for (int ks = 0; ks < 4; ++ks) {
            size_t off = (size_t)row * DIM + ks * 16 + h * 8;
            cH[ct][ks] = __builtin_bit_cast(half8, *(const short8*)(chi_g + off));
        }
    }

    const int p_st  = tid >> 4;
    const int dgrp  = tid & 15;
    const int f_st  = dgrp >> 1;
    const int half  = dgrp & 1;
    const int widx  = f_st * 128 + ((p_st ^ (f_st & 7)) << 2) + half * 2;

    const size_t xbase = (size_t)blockIdx.x * 32768 + tid * 4;

#define STAGE(buf, v4)                                                        \
    {                                                                         \
        uint2 w2 = cvt4_f16(v4);                                              \
        *(uint2*)&lds_x[buf][widx] = w2;                                      \
    }

    float4 pf = *(const float4*)(x + xbase);
    STAGE(0, pf)
    pf = *(const float4*)(x + xbase + 2048);
    __syncthreads();

    // bias into VGPRs (read once; reused read-only as ks=0 MFMA C-in)
    f32x16 bias0, bias1;
    {
        const float4* b0 = (const float4*)&lds_bias[wave * 64 + h * 16];
        const float4* b1 = (const float4*)&lds_bias[wave * 64 + 32 + h * 16];
#pragma unroll
        for (int g = 0; g < 4; ++g) {
            float4 a = b0[g], bb = b1[g];
            bias0[4*g+0] = a.x;  bias0[4*g+1] = a.y;  bias0[4*g+2] = a.z;  bias0[4*g+3] = a.w;
            bias1[4*g+0] = bb.x; bias1[4*g+1] = bb.y; bias1[4*g+2] = bb.z; bias1[4*g+3] = bb.w;
        }
    }

    const unsigned int base_id = wave * 64 + 4 * h;

    for (int t = 0; t < 16; ++t) {
        const int b = t & 1;
        if (t < 15) STAGE(b ^ 1, pf)
        if (t < 14) pf = *(const float4*)(x + xbase + (size_t)(t + 2) * 2048);

        f32x16 acc0, acc1;
        {   // ks = 0: bias is the C operand (no init movs)
            const int ridx = h * 128 + ((l31 ^ (h & 7)) << 2);
            half8 xh = __builtin_bit_cast(half8, *(const short8*)&lds_x[b][ridx]);
            acc0 = __builtin_amdgcn_mfma_f32_32x32x16_f16(cH[0][0], xh, bias0, 0, 0, 0);
            acc1 = __builtin_amdgcn_mfma_f32_32x32x16_f16(cH[1][0], xh, bias1, 0, 0, 0);
        }
#pragma unroll
        for (int ks = 1; ks < 4; ++ks) {
            const int f = ks * 2 + h;
            const int ridx = f * 128 + ((l31 ^ (f & 7)) << 2);
            half8 xh = __builtin_bit_cast(half8, *(const short8*)&lds_x[b][ridx]);
            acc0 = __builtin_amdgcn_mfma_f32_32x32x16_f16(cH[0][ks], xh, acc0, 0, 0, 0);
            acc1 = __builtin_amdgcn_mfma_f32_32x32x16_f16(cH[1][ks], xh, acc1, 0, 0, 0);
        }

        // exact in-lane argmin (ids ascending -> strict < = first occurrence)
        float bv = acc0[0];
        unsigned int boff = 0;
#pragma unroll
        for (int r = 1; r < 16; ++r) {
            unsigned int off = (r & 3) + 8 * (r >> 2);
            if (acc0[r] < bv) { bv = acc0[r]; boff = off; }
        }
#pragma unroll
        for (int r = 0; r < 16; ++r) {
            unsigned int off = 32 + (r & 3) + 8 * (r >> 2);
            if (acc1[r] < bv) { bv = acc1[r]; boff = off; }
        }

        unsigned int ub = __builtin_bit_cast(unsigned int, bv);
        ub ^= (unsigned int)(((int)ub) >> 31) | 0x80000000u;
        unsigned long long pk =
            ((unsigned long long)ub << 32) | (unsigned long long)(base_id + boff);
        atomicMin(&lds_best[t * 32 + l31], pk);
        __syncthreads();
    }
#undef STAGE

    assign[blockIdx.x * 512 + tid] = (unsigned int)(lds_best[tid] & 0xFFFFFFFFu);
}

// ---------------------------------------------------------------------------
// reduce v5 (unchanged): one-hot MFMA, bf16-hi B operand; slab or atomic flush.
// ---------------------------------------------------------------------------
template <int SLAB>
__global__ __launch_bounds__(512)
void reduce_kernel(const float* __restrict__ x,
                   const unsigned int* __restrict__ assign,
                   float* __restrict__ gsums, float* __restrict__ gcnt,
                   unsigned int* __restrict__ slab_u32,
                   float* __restrict__ cnt_slab, int nsc) {
    __shared__ unsigned short lds_h[2][64][128];
    __shared__ unsigned int   lds_a[2][128];
    __shared__ float          lds_cnt[K_CL];

    const int tid  = threadIdx.x;
    const int wave = tid >> 6;
    const int lane = tid & 63;
    const int l31  = lane & 31;
    const int h    = lane >> 5;
    const int d    = lane;
    const int pg   = wave;

    lds_cnt[tid] = 0.f;

    const size_t pbase = (size_t)blockIdx.x * (size_t)(nsc * 128);

    float f[16];
    {
        const float* xp = x + (pbase + pg * 16) * DIM + d;
#pragma unroll
        for (int i = 0; i < 16; ++i) f[i] = xp[(size_t)i * DIM];
    }
    __syncthreads();

    for (int i = 0; i < (nsc >> 2); ++i)
        atomicAdd(&lds_cnt[assign[pbase + tid + i * 512]], 1.f);

    const int swz = (d & 15) << 3;

#define WRITE_BUF(b)                                                          \
    {                                                                         \
        unsigned int hw[8];                                                   \
        _Pragma("unroll")                                                     \
        for (int q = 0; q < 8; ++q) hw[q] = pk_bf16(f[2*q], f[2*q+1]);        \
        unsigned short* rh = &lds_h[b][d][0];                                 \
        const int j0 = (pg * 16) ^ swz;                                       \
        const int j1 = (pg * 16 + 8) ^ swz;                                   \
        uint4 u;                                                              \
        u.x=hw[0]; u.y=hw[1]; u.z=hw[2]; u.w=hw[3]; *(uint4*)&rh[j0] = u;     \
        u.x=hw[4]; u.y=hw[5]; u.z=hw[6]; u.w=hw[7]; *(uint4*)&rh[j1] = u;     \
    }

    WRITE_BUF(0)
    if (tid < 32) {
        uint4 av = *(const uint4*)(assign + pbase + tid * 4);
        *(uint4*)&lds_a[0][tid * 4] = av;
    }
    __syncthreads();

    const unsigned int row0 = wave * 64 + l31;
    const unsigned int row1 = row0 + 32;
    f32x16 C00 = {}, C01 = {}, C10 = {}, C11 = {};

    for (int sc = 0; sc < nsc; ++sc) {
        const int b = sc & 1;
        if (sc < nsc - 1) {
            const float* xp = x + (pbase + (size_t)(sc + 1) * 128 + pg * 16) * DIM + d;
#pragma unroll
            for (int i = 0; i < 16; ++i) f[i] = xp[(size_t)i * DIM];
        }

#pragma unroll
        for (int c = 0; c < 8; ++c) {
            const unsigned int* ap = &lds_a[b][c * 16 + 8 * h];
            uint4 aA = *(const uint4*)ap;
            uint4 aB = *(const uint4*)(ap + 4);
            unsigned int a[8] = {aA.x, aA.y, aA.z, aA.w, aB.x, aB.y, aB.z, aB.w};
            unsigned int i0[4], i1[4];
#pragma unroll
            for (int q = 0; q < 4; ++q) {
                i0[q] = (a[2*q]==row0 ? 0x3F80u : 0u) | (a[2*q+1]==row0 ? 0x3F800000u : 0u);
                i1[q] = (a[2*q]==row1 ? 0x3F80u : 0u) | (a[2*q+1]==row1 ? 0x3F800000u : 0u);
            }
            uint4 u0; u0.x=i0[0]; u0.y=i0[1]; u0.z=i0[2]; u0.w=i0[3];
            uint4 u1; u1.x=i1[0]; u1.y=i1[1]; u1.z=i1[2]; u1.w=i1[3];
            short8 A0 = __builtin_bit_cast(short8, u0);
            short8 A1 = __builtin_bit_cast(short8, u1);

            const int off = (c * 16 + 8 * h) ^ ((l31 & 15) << 3);
            short8 xh0 = *(const short8*)&lds_h[b][l31][off];
            short8 xh1 = *(const short8*)&lds_h[b][l31 + 32][off];

            C00 = __builtin_amdgcn_mfma_f32_32x32x16_bf16(A0, xh0, C00, 0, 0, 0);
            C01 = __builtin_amdgcn_mfma_f32_32x32x16_bf16(A0, xh1, C01, 0, 0, 0);
            C10 = __builtin_amdgcn_mfma_f32_32x32x16_bf16(A1, xh0, C10, 0, 0, 0);
            C11 = __builtin_amdgcn_mfma_f32_32x32x16_bf16(A1, xh1, C11, 0, 0, 0);
        }
        __syncthreads();

        if (sc < nsc - 1) {
            WRITE_BUF(b ^ 1)
            if (tid < 32) {
                uint4 av = *(const uint4*)(assign + pbase + (size_t)(sc + 1) * 128 + tid * 4);
                *(uint4*)&lds_a[b ^ 1][tid * 4] = av;
            }
            __syncthreads();
        }
    }
#undef WRITE_BUF

    if (SLAB) {
        cnt_slab[blockIdx.x * K_CL + tid] = lds_cnt[tid];
        unsigned int* myslab = slab_u32 + (size_t)blockIdx.x * 16384;
#pragma unroll
        for (int r = 0; r < 16; ++r) {
            int ro = (r & 3) + 8 * (r >> 2) + 4 * h;
            int k0 = wave * 64 + ro;
            myslab[k0 * 32 + l31]        = pk_bf16(C00[r], C01[r]);
            myslab[(k0 + 32) * 32 + l31] = pk_bf16(C10[r], C11[r]);
        }
    } else {
        atomicAdd(&gcnt[tid], lds_cnt[tid]);
#pragma unroll
        for (int rr = 0; rr < 16; ++rr) {
            int r = (rr + (int)(blockIdx.x & 15)) & 15;
            int ro = (r & 3) + 8 * (r >> 2) + 4 * h;
            atomicAdd(&gsums[(wave * 64 + ro) * DIM + l31],           C00[r]);
            atomicAdd(&gsums[(wave * 64 + ro) * DIM + 32 + l31],      C01[r]);
            atomicAdd(&gsums[(wave * 64 + 32 + ro) * DIM + l31],      C10[r]);
            atomicAdd(&gsums[(wave * 64 + 32 + ro) * DIM + 32 + l31], C11[r]);
        }
    }
}

// ---------------------------------------------------------------------------
// final (slab) v3 (unchanged): csum merged; 256 blocks x 512 thr.
// ---------------------------------------------------------------------------
__global__ __launch_bounds__(512)
void final_slab_kernel(const unsigned int* __restrict__ slab,
                       const float* __restrict__ cnt_slab,
                       const float* __restrict__ centers,
                       float* __restrict__ out, int P) {
    __shared__ float s0b[8][64], s1b[8][64];
    __shared__ float cfin[2];
    const int tid = threadIdx.x;
    const int q   = tid >> 6;
    const int gl  = tid & 63;
    const int gid = blockIdx.x * 64 + gl;

    float s0 = 0.f, s1 = 0.f;
    for (int b = q; b < P; b += 8) {
        unsigned int u = slab[(size_t)b * 16384 + gid];
        s0 += __builtin_bit_cast(float, u << 16);
        s1 += __builtin_bit_cast(float, u & 0xFFFF0000u);
    }
    s0b[q][gl] = s0; s1b[q][gl] = s1;

    if (tid < 128) {
        const int hf = tid >> 6;
        const int ln = tid & 63;
        const int k  = blockIdx.x * 2 + hf;
        float cp = 0.f;
#pragma unroll
        for (int j = 0; j < 8; ++j)
            cp += cnt_slab[(ln + 64 * j) * K_CL + k];
#pragma unroll
        for (int off = 1; off < 64; off <<= 1) cp += __shfl_xor(cp, off, 64);
        if (ln == 0) cfin[hf] = cp;
    }
    __syncthreads();

    if (tid < 64) {
        float t0 = 0.f, t1 = 0.f;
#pragma unroll
        for (int j = 0; j < 8; ++j) { t0 += s0b[j][tid]; t1 += s1b[j][tid]; }
        const int g = blockIdx.x * 64 + tid;
        const int k = g >> 5, p = g & 31;
        float c = cfin[(tid >> 5)];
        if (c > 0.f) {
            out[k * DIM + p]      = t0 / c;
            out[k * DIM + 32 + p] = t1 / c;
        } else {
            out[k * DIM + p]      = centers[k * DIM + p];
            out[k * DIM + 32 + p] = centers[k * DIM + 32 + p];
        }
        if (p == 0) out[K_CL * DIM + k] = c;
    }
}

// ---------------------------------------------------------------------------
// final (atomic fallback path)
// ---------------------------------------------------------------------------
__global__ void final_kernel(const float* __restrict__ gsums,
                             const float* __restrict__ gcnt,
                             const float* __restrict__ centers,
                             float* __restrict__ out) {
    int i = blockIdx.x * 256 + threadIdx.x;
    if (i < K_CL * DIM) {
        int k = i >> 6;
        float c = gcnt[k];
        out[i] = (c > 0.f) ? (gsums[i] / c) : centers[i];
    } else if (i < OUTSZ) {
        out[i] = gcnt[i - K_CL * DIM];
    }
}

extern "C" void kernel_launch(void* const* d_in, const int* in_sizes, int n_in,
                              void* d_out, int out_size, void* d_ws, size_t ws_size,
                              hipStream_t stream) {
    const float* x       = (const float*)d_in[0];
    const float* centers = (const float*)d_in[1];

    char* ws = (char*)d_ws;
    unsigned short* chi    = (unsigned short*)(ws);             // 64 KiB (fp16)
    float*          hc2    = (float*)(ws + 131072);             // 2 KiB
    unsigned int*   assign = (unsigned int*)(ws + 133120);      // 2 MiB
    float*          gsums  = (float*)(ws + 2230272);            // 128 KiB
    float*          gcnt   = (float*)(ws + 2361344);            // 2 KiB
    const size_t    fixed  = 2363392;
    unsigned int*   slab_u32 = (unsigned int*)(ws + fixed);              // 32 MiB
    float*          cnt_slab = (float*)(ws + fixed + (size_t)512*16384*4); // 1 MiB
    const size_t    need = fixed + (size_t)512*16384*4 + (size_t)512*K_CL*4;

    prep_kernel<<<K_CL, 64, 0, stream>>>(centers, chi, hc2);
    assign_kernel<<<1024, 512, 0, stream>>>(x, chi, hc2, assign);

    if (ws_size >= need) {
        reduce_kernel<1><<<512, 512, 0, stream>>>(x, assign, gsums, gcnt,
                                                  slab_u32, cnt_slab, 8);
        final_slab_kernel<<<256, 512, 0, stream>>>(slab_u32, cnt_slab, centers,
                                                   (float*)d_out, 512);
    } else {
        hipMemsetAsync(gsums, 0, (K_CL * DIM + K_CL) * sizeof(float), stream);
        reduce_kernel<0><<<256, 512, 0, stream>>>(x, assign, gsums, gcnt,
                                                  slab_u32, cnt_slab, 16);
        final_kernel<<<(OUTSZ + 255) / 256, 256, 0, stream>>>(
            gsums, gcnt, centers, (float*)d_out);
    }
}